// Round 2
// baseline (758.272 us; speedup 1.0000x reference)
//
#include <hip/hip_runtime.h>
#include <hip/hip_bf16.h>

#define N_TOK 8192
#define DM 1024
#define KD 64
#define QKV_COLS 192
#define ODIM 1024
#define QT 16
#define KT 64
#define KPAD 68

// ---------------- Kernel 1: QKV projection ----------------
// grid = N/8 blocks, 192 threads. Each block: 8 rows x 192 cols, K=1024.
__global__ __launch_bounds__(192) void qkv_kernel(
    const float* __restrict__ x,
    const float* __restrict__ w,
    const float* __restrict__ b,
    float* __restrict__ q, float* __restrict__ k, float* __restrict__ v)
{
    __shared__ float xs[8 * DM];
    const int tid = threadIdx.x;
    const int row0 = blockIdx.x * 8;
    for (int i = tid; i < 8 * DM; i += 192)
        xs[i] = x[row0 * DM + i];
    __syncthreads();
    const int col = tid;  // 0..191
    float acc[8];
    const float bias = b[col];
#pragma unroll
    for (int r = 0; r < 8; ++r) acc[r] = bias;
    for (int d = 0; d < DM; d += 4) {
        const float w0 = w[(d + 0) * QKV_COLS + col];
        const float w1 = w[(d + 1) * QKV_COLS + col];
        const float w2 = w[(d + 2) * QKV_COLS + col];
        const float w3 = w[(d + 3) * QKV_COLS + col];
#pragma unroll
        for (int r = 0; r < 8; ++r) {
            const float4 xv = *(const float4*)(&xs[r * DM + d]);
            acc[r] += xv.x * w0 + xv.y * w1 + xv.z * w2 + xv.w * w3;
        }
    }
    float* dst = (col < 64) ? q : (col < 128) ? k : v;
    const int c = col & 63;
#pragma unroll
    for (int r = 0; r < 8; ++r)
        dst[(row0 + r) * KD + c] = acc[r];
}

// ---------------- Kernel 2: causal flash attention ----------------
// grid = N/QT blocks (reverse-scheduled), 256 threads = 4 waves.
// Wave w owns Q-rows 4w..4w+3. QK^T: lane = key col. PV: lane = head dim.
__global__ __launch_bounds__(256) void attn_kernel(
    const float* __restrict__ q, const float* __restrict__ k,
    const float* __restrict__ v, float* __restrict__ ao,
    const int* __restrict__ causal_p)
{
    __shared__ float Qs[QT * KD];        // 16x64
    __shared__ float Ks[KT * KPAD];      // 64x68 (pad: 16B-aligned float4 rows)
    __shared__ float VTs[KD * KPAD];     // V transposed: VTs[d][j] = V[j][d]
    __shared__ float Ps[QT * KT];        // probs, wave-private rows

    const int tid = threadIdx.x;
    const int wv = tid >> 6;
    const int lane = tid & 63;
    const int qt = (int)gridDim.x - 1 - (int)blockIdx.x;  // heavy blocks first
    const int R0 = qt * QT;
    const int causal = *causal_p;

    for (int i = tid; i < QT * KD; i += 256)
        Qs[i] = q[R0 * KD + i];

    const int ntiles = causal ? ((R0 + QT - 1) / KT + 1) : (N_TOK / KT);

    float runm[4], runl[4], o[4];
#pragma unroll
    for (int m = 0; m < 4; ++m) { runm[m] = -3.0e38f; runl[m] = 0.f; o[m] = 0.f; }

    for (int t = 0; t < ntiles; ++t) {
        __syncthreads();  // previous tile's PV reads done before overwrite
        const int t0 = t * KT;
        for (int i = tid; i < KT * KD; i += 256) {
            const int j = i >> 6, d = i & 63;
            Ks[j * KPAD + d] = k[(t0 + j) * KD + d];
            VTs[d * KPAD + j] = v[(t0 + j) * KD + d];
        }
        __syncthreads();

        // S[r][lane] = sum_d Q[r][d] * K[lane][d]
        float s[4] = {0.f, 0.f, 0.f, 0.f};
        const float* kp = &Ks[lane * KPAD];
#pragma unroll
        for (int d = 0; d < KD; d += 4) {
            const float4 k4 = *(const float4*)(kp + d);
#pragma unroll
            for (int m = 0; m < 4; ++m) {
                const float4 q4 = *(const float4*)(&Qs[(4 * wv + m) * KD + d]);
                s[m] += q4.x * k4.x + q4.y * k4.y + q4.z * k4.z + q4.w * k4.w;
            }
        }

        const int jg = t0 + lane;
#pragma unroll
        for (int m = 0; m < 4; ++m) {
            const int rg = R0 + 4 * wv + m;
            const bool valid = (!causal) || (jg <= rg);
            float tm = valid ? s[m] : -3.0e38f;
#pragma unroll
            for (int off = 32; off > 0; off >>= 1)
                tm = fmaxf(tm, __shfl_xor(tm, off));
            const float nm = fmaxf(runm[m], tm);
            const float al = __expf(runm[m] - nm);
            const float p = valid ? __expf(s[m] - nm) : 0.f;
            float ts = p;
#pragma unroll
            for (int off = 32; off > 0; off >>= 1)
                ts += __shfl_xor(ts, off);
            runl[m] = runl[m] * al + ts;
            o[m] *= al;
            runm[m] = nm;
            Ps[(4 * wv + m) * KT + lane] = p;  // wave-private row
        }

        // O[r][lane] += sum_j P[r][j] * V[j][lane]
        const float* vp = &VTs[lane * KPAD];
#pragma unroll
        for (int j = 0; j < KT; j += 4) {
            const float4 v4 = *(const float4*)(vp + j);
#pragma unroll
            for (int m = 0; m < 4; ++m) {
                const float4 p4 = *(const float4*)(&Ps[(4 * wv + m) * KT + j]);
                o[m] += p4.x * v4.x + p4.y * v4.y + p4.z * v4.z + p4.w * v4.w;
            }
        }
    }

#pragma unroll
    for (int m = 0; m < 4; ++m)
        ao[(R0 + 4 * wv + m) * KD + lane] = o[m] / runl[m];
}

// ---------------- Kernel 3: output projection ----------------
// grid = N/4 blocks, 256 threads. Each block: 4 rows x 1024 cols, K=64.
__global__ __launch_bounds__(256) void proj_kernel(
    const float* __restrict__ ao, const float* __restrict__ w,
    const float* __restrict__ b, float* __restrict__ out)
{
    __shared__ float As[4 * KD];
    const int tid = threadIdx.x;
    const int row0 = blockIdx.x * 4;
    As[tid] = ao[row0 * KD + tid];  // 256 elements exactly
    __syncthreads();

    float acc[4][4];
#pragma unroll
    for (int ci = 0; ci < 4; ++ci) {
        const float bb = b[tid + ci * 256];
#pragma unroll
        for (int r = 0; r < 4; ++r) acc[r][ci] = bb;
    }
#pragma unroll 4
    for (int d = 0; d < KD; ++d) {
        const float a0 = As[0 * KD + d];
        const float a1 = As[1 * KD + d];
        const float a2 = As[2 * KD + d];
        const float a3 = As[3 * KD + d];
#pragma unroll
        for (int ci = 0; ci < 4; ++ci) {
            const float wv = w[d * ODIM + tid + ci * 256];
            acc[0][ci] += a0 * wv;
            acc[1][ci] += a1 * wv;
            acc[2][ci] += a2 * wv;
            acc[3][ci] += a3 * wv;
        }
    }
#pragma unroll
    for (int r = 0; r < 4; ++r)
#pragma unroll
        for (int ci = 0; ci < 4; ++ci)
            out[(row0 + r) * ODIM + tid + ci * 256] = acc[r][ci];
}

extern "C" void kernel_launch(void* const* d_in, const int* in_sizes, int n_in,
                              void* d_out, int out_size, void* d_ws, size_t ws_size,
                              hipStream_t stream) {
    const float* x     = (const float*)d_in[0];
    const float* w_qkv = (const float*)d_in[1];
    const float* b_qkv = (const float*)d_in[2];
    const float* w_out = (const float*)d_in[3];
    const float* b_out = (const float*)d_in[4];
    const int* causal  = (const int*)d_in[5];
    float* out         = (float*)d_out;

    float* ws = (float*)d_ws;
    const size_t NKD = (size_t)N_TOK * KD;  // 524288 floats
    float* q  = ws;
    float* k  = ws + NKD;
    float* v  = ws + 2 * NKD;
    float* ao = ws + 3 * NKD;

    qkv_kernel<<<N_TOK / 8, 192, 0, stream>>>(x, w_qkv, b_qkv, q, k, v);
    attn_kernel<<<N_TOK / QT, 256, 0, stream>>>(q, k, v, ao, causal);
    proj_kernel<<<N_TOK / 4, 256, 0, stream>>>(ao, w_out, b_out, out);
}

// Round 3
// 307.814 us; speedup vs baseline: 2.4634x; 2.4634x over previous
//
#include <hip/hip_runtime.h>
#include <hip/hip_bf16.h>

#define N_TOK 8192
#define DM 1024
#define KD 64
#define QKV_COLS 192
#define ODIM 1024
#define RB 32            // attention Q-rows per block

typedef unsigned short ushort_t;
typedef __attribute__((ext_vector_type(8))) short short8;
typedef __attribute__((ext_vector_type(4))) short short4v;
typedef __attribute__((ext_vector_type(4))) float f32x4;

__device__ __forceinline__ ushort_t f2bf(float x) {
    __hip_bfloat16 h = __float2bfloat16(x);
    return *(ushort_t*)&h;
}
#define MFMA16(a, b, c) __builtin_amdgcn_mfma_f32_16x16x32_bf16((a), (b), (c), 0, 0, 0)

// ---------------- Kernel 1: QKV projection (fp32 VALU) ----------------
// grid = N/8, 192 threads. Emits bf16 q[tok][64], k[tok][64], vT[64][tok].
__global__ __launch_bounds__(192) void qkv_kernel(
    const float* __restrict__ x,
    const float* __restrict__ w,
    const float* __restrict__ b,
    ushort_t* __restrict__ qb, ushort_t* __restrict__ kbf, ushort_t* __restrict__ vT)
{
    __shared__ float xs[8 * DM];
    const int tid = threadIdx.x;
    const int row0 = blockIdx.x * 8;
    for (int i = tid; i < 8 * DM; i += 192)
        xs[i] = x[row0 * DM + i];
    __syncthreads();
    const int col = tid;
    float acc[8];
    const float bias = b[col];
#pragma unroll
    for (int r = 0; r < 8; ++r) acc[r] = bias;
    for (int d = 0; d < DM; d += 4) {
        const float w0 = w[(d + 0) * QKV_COLS + col];
        const float w1 = w[(d + 1) * QKV_COLS + col];
        const float w2 = w[(d + 2) * QKV_COLS + col];
        const float w3 = w[(d + 3) * QKV_COLS + col];
#pragma unroll
        for (int r = 0; r < 8; ++r) {
            const float4 xv = *(const float4*)(&xs[r * DM + d]);
            acc[r] += xv.x * w0 + xv.y * w1 + xv.z * w2 + xv.w * w3;
        }
    }
    if (col < 64) {
#pragma unroll
        for (int r = 0; r < 8; ++r)
            qb[(row0 + r) * KD + col] = f2bf(acc[r]);
    } else if (col < 128) {
        const int c = col - 64;
#pragma unroll
        for (int r = 0; r < 8; ++r)
            kbf[(row0 + r) * KD + c] = f2bf(acc[r]);
    } else {
        const int c = col - 128;
        union { ushort_t u[8]; uint4 v; } pk;
#pragma unroll
        for (int r = 0; r < 8; ++r) pk.u[r] = f2bf(acc[r]);
        *(uint4*)&vT[c * N_TOK + row0] = pk.v;  // (c*8192+row0)*2 is 16B-aligned
    }
}

// ---------------- Kernel 2: MFMA causal flash attention ----------------
// grid 256 blocks x 256 thr. Block: 32 Q-rows. Wave (rg,kp): rows rg*16..+16,
// key-tiles of parity kp. Two 64-key K/VT tiles staged per iter. 2-way merge.
__global__ __launch_bounds__(256) void attn_kernel(
    const ushort_t* __restrict__ qb, const ushort_t* __restrict__ kbf,
    const ushort_t* __restrict__ vT, float* __restrict__ ao,
    const int* __restrict__ causal_p)
{
    __shared__ ushort_t Qs[32 * 72];          // 4.6 KB
    __shared__ ushort_t KVs[4 * 64 * 72];     // K0,K1,VT0,VT1 : 36.9 KB
    __shared__ ushort_t Ps[4 * 16 * 76];      // per-wave P : 9.7 KB

    const int tid = threadIdx.x;
    const int wv = tid >> 6;
    const int lane = tid & 63;
    const int g = lane >> 4;     // quad
    const int i = lane & 15;
    const int rg = wv & 1;       // row group
    const int kp = wv >> 1;      // key parity
    const int qt = (int)gridDim.x - 1 - (int)blockIdx.x;  // heavy first
    const int R0 = qt * RB;
    const int causal = *causal_p;

    { // stage Q: 32x64 bf16, LDS stride 72
        const int row = tid >> 3, ch = tid & 7;
        *(uint4*)&Qs[row * 72 + ch * 8] = *(const uint4*)&qb[(R0 + row) * KD + ch * 8];
    }
    __syncthreads();

    // Q A-frags (loop-invariant): A[m=i][k=kc*32+g*8+jj]
    const short8 qf0 = *(const short8*)&Qs[(rg * 16 + i) * 72 + g * 8];
    const short8 qf1 = *(const short8*)&Qs[(rg * 16 + i) * 72 + 32 + g * 8];

    const int nkt = causal ? (R0 + RB + 63) / 64 : (N_TOK / 64);
    const int iters = (nkt + 1) >> 1;

    const f32x4 zero4 = {0.f, 0.f, 0.f, 0.f};
    f32x4 o4[4];
    float runm[4], runl[4];
#pragma unroll
    for (int ct = 0; ct < 4; ++ct) o4[ct] = zero4;
#pragma unroll
    for (int r = 0; r < 4; ++r) { runm[r] = -1e30f; runl[r] = 0.f; }

    for (int it = 0; it < iters; ++it) {
        __syncthreads();
        const int kb0 = it * 128;
        // stage 2 K tiles + 2 VT tiles (each 64x64 bf16, LDS stride 72)
#pragma unroll
        for (int n = 0; n < 4; ++n) {
            const int idx = n * 256 + tid;           // [0,1024)
            const int t = idx >> 9, rem = idx & 511;
            const int row = rem >> 3, ch = rem & 7;
            *(uint4*)&KVs[(t * 64 + row) * 72 + ch * 8] =
                *(const uint4*)&kbf[(kb0 + t * 64 + row) * KD + ch * 8];
            *(uint4*)&KVs[((2 + t) * 64 + row) * 72 + ch * 8] =
                *(const uint4*)&vT[row * N_TOK + kb0 + t * 64 + ch * 8];
        }
        __syncthreads();

        const int kbw = kb0 + kp * 64;
        const ushort_t* Kt = &KVs[(kp * 64) * 72];
        const ushort_t* Vt = &KVs[((2 + kp) * 64) * 72];

        // S = Q K^T : per col-tile ct, 2 MFMAs (K=64)
        f32x4 s4[4];
#pragma unroll
        for (int ct = 0; ct < 4; ++ct) {
            const short8 kf0 = *(const short8*)&Kt[(ct * 16 + i) * 72 + g * 8];
            const short8 kf1 = *(const short8*)&Kt[(ct * 16 + i) * 72 + 32 + g * 8];
            f32x4 acc = MFMA16(qf0, kf0, zero4);
            s4[ct] = MFMA16(qf1, kf1, acc);
        }

        // online softmax (rows live across 16 lanes i; row = 4g+reg)
        const int pb = wv * (16 * 76);
#pragma unroll
        for (int reg = 0; reg < 4; ++reg) {
            const int qrow = R0 + rg * 16 + 4 * g + reg;
            float mx = -1e30f;
#pragma unroll
            for (int ct = 0; ct < 4; ++ct) {
                const bool vm = (!causal) || (kbw + ct * 16 + i <= qrow);
                mx = fmaxf(mx, vm ? s4[ct][reg] : -1e30f);
            }
            mx = fmaxf(mx, __shfl_xor(mx, 1));
            mx = fmaxf(mx, __shfl_xor(mx, 2));
            mx = fmaxf(mx, __shfl_xor(mx, 4));
            mx = fmaxf(mx, __shfl_xor(mx, 8));
            const float nm = fmaxf(runm[reg], mx);
            const float al = __expf(runm[reg] - nm);
            runm[reg] = nm;
            float rs = 0.f;
#pragma unroll
            for (int ct = 0; ct < 4; ++ct) {
                const bool vm = (!causal) || (kbw + ct * 16 + i <= qrow);
                const float pv = vm ? __expf(s4[ct][reg] - nm) : 0.f;
                rs += pv;
                Ps[pb + (4 * g + reg) * 76 + ct * 16 + i] = f2bf(pv);
            }
            rs += __shfl_xor(rs, 1);
            rs += __shfl_xor(rs, 2);
            rs += __shfl_xor(rs, 4);
            rs += __shfl_xor(rs, 8);
            runl[reg] = runl[reg] * al + rs;
#pragma unroll
            for (int ct = 0; ct < 4; ++ct) o4[ct][reg] *= al;
        }

        // P A-frags from LDS (wave-private; compiler orders lgkmcnt)
        short8 pf0, pf1;
        {
            union { short8 v8; short4v h[2]; } u0, u1;
            const int pbase = pb + i * 76 + g * 8;
            u0.h[0] = *(const short4v*)&Ps[pbase];
            u0.h[1] = *(const short4v*)&Ps[pbase + 4];
            u1.h[0] = *(const short4v*)&Ps[pbase + 32];
            u1.h[1] = *(const short4v*)&Ps[pbase + 36];
            pf0 = u0.v8; pf1 = u1.v8;
        }

        // O += P V : B[n=vcol][k=key] from VT tile
#pragma unroll
        for (int ct = 0; ct < 4; ++ct) {
            const short8 vf0 = *(const short8*)&Vt[(ct * 16 + i) * 72 + g * 8];
            const short8 vf1 = *(const short8*)&Vt[(ct * 16 + i) * 72 + 32 + g * 8];
            o4[ct] = MFMA16(pf0, vf0, o4[ct]);
            o4[ct] = MFMA16(pf1, vf1, o4[ct]);
        }
    }

    // merge the two key-parity partials per row group
    __syncthreads();
    float* Om = (float*)KVs;   // [wv][16][64]
    float* ml = (float*)Ps;    // [wv][2][16]
#pragma unroll
    for (int ct = 0; ct < 4; ++ct)
#pragma unroll
        for (int reg = 0; reg < 4; ++reg)
            Om[wv * 1024 + (4 * g + reg) * 64 + ct * 16 + i] = o4[ct][reg];
    if (i == 0) {
#pragma unroll
        for (int reg = 0; reg < 4; ++reg) {
            ml[wv * 32 + (4 * g + reg)] = runm[reg];
            ml[wv * 32 + 16 + (4 * g + reg)] = runl[reg];
        }
    }
    __syncthreads();
    if (kp == 0) {
        const int pw = wv + 2;
#pragma unroll
        for (int reg = 0; reg < 4; ++reg) {
            const int r = 4 * g + reg;
            const float m1 = ml[pw * 32 + r];
            const float l1 = ml[pw * 32 + 16 + r];
            const float M = fmaxf(runm[reg], m1);
            const float e0 = __expf(runm[reg] - M);
            const float e1 = __expf(m1 - M);
            const float inv = 1.f / (runl[reg] * e0 + l1 * e1);
#pragma unroll
            for (int ct = 0; ct < 4; ++ct) {
                const float ov = (o4[ct][reg] * e0 + Om[pw * 1024 + r * 64 + ct * 16 + i] * e1) * inv;
                ao[(R0 + rg * 16 + r) * KD + ct * 16 + i] = ov;
            }
        }
    }
}

// ---------------- Kernel 3: output projection (fp32 VALU) ----------------
__global__ __launch_bounds__(256) void proj_kernel(
    const float* __restrict__ ao, const float* __restrict__ w,
    const float* __restrict__ b, float* __restrict__ out)
{
    __shared__ float As[4 * KD];
    const int tid = threadIdx.x;
    const int row0 = blockIdx.x * 4;
    As[tid] = ao[row0 * KD + tid];
    __syncthreads();

    float acc[4][4];
#pragma unroll
    for (int ci = 0; ci < 4; ++ci) {
        const float bb = b[tid + ci * 256];
#pragma unroll
        for (int r = 0; r < 4; ++r) acc[r][ci] = bb;
    }
#pragma unroll 4
    for (int d = 0; d < KD; ++d) {
        const float a0 = As[0 * KD + d];
        const float a1 = As[1 * KD + d];
        const float a2 = As[2 * KD + d];
        const float a3 = As[3 * KD + d];
#pragma unroll
        for (int ci = 0; ci < 4; ++ci) {
            const float wv = w[d * ODIM + tid + ci * 256];
            acc[0][ci] += a0 * wv;
            acc[1][ci] += a1 * wv;
            acc[2][ci] += a2 * wv;
            acc[3][ci] += a3 * wv;
        }
    }
#pragma unroll
    for (int r = 0; r < 4; ++r)
#pragma unroll
        for (int ci = 0; ci < 4; ++ci)
            out[(row0 + r) * ODIM + tid + ci * 256] = acc[r][ci];
}

extern "C" void kernel_launch(void* const* d_in, const int* in_sizes, int n_in,
                              void* d_out, int out_size, void* d_ws, size_t ws_size,
                              hipStream_t stream) {
    const float* x     = (const float*)d_in[0];
    const float* w_qkv = (const float*)d_in[1];
    const float* b_qkv = (const float*)d_in[2];
    const float* w_out = (const float*)d_in[3];
    const float* b_out = (const float*)d_in[4];
    const int* causal  = (const int*)d_in[5];
    float* out         = (float*)d_out;

    char* ws = (char*)d_ws;
    ushort_t* qb  = (ushort_t*)(ws);                         // 1 MB
    ushort_t* kbf = (ushort_t*)(ws + (1u << 20));            // 1 MB
    ushort_t* vT  = (ushort_t*)(ws + (2u << 20));            // 1 MB
    float*    ao  = (float*)(ws + (3u << 20));               // 2 MB

    qkv_kernel<<<N_TOK / 8, 192, 0, stream>>>(x, w_qkv, b_qkv, qb, kbf, vT);
    attn_kernel<<<N_TOK / RB, 256, 0, stream>>>(qb, kbf, vT, ao, causal);
    proj_kernel<<<N_TOK / 4, 256, 0, stream>>>(ao, w_out, b_out, out);
}

// Round 4
// 302.613 us; speedup vs baseline: 2.5057x; 1.0172x over previous
//
#include <hip/hip_runtime.h>
#include <hip/hip_bf16.h>

#define N_TOK 8192
#define DM 1024
#define KD 64
#define ODIM 1024

typedef unsigned short ushort_t;
typedef __attribute__((ext_vector_type(8))) short short8;
typedef __attribute__((ext_vector_type(4))) short short4v;
typedef __attribute__((ext_vector_type(4))) float f32x4;

#define MFMA16(a, b, c) __builtin_amdgcn_mfma_f32_16x16x32_bf16((a), (b), (c), 0, 0, 0)

__device__ __forceinline__ ushort_t f2bf(float x) {
    __hip_bfloat16 h = __float2bfloat16(x);
    return *(ushort_t*)&h;
}
__device__ __forceinline__ float bf2f(ushort_t u) {
    __hip_bfloat16 h = *(__hip_bfloat16*)&u;
    return __bfloat162float(h);
}
// Dekker-style split: x ~= hi + lo, both bf16. Residual ~2^-17 relative.
__device__ __forceinline__ void split2(float x, ushort_t& hi, ushort_t& lo) {
    hi = f2bf(x);
    lo = f2bf(x - bf2f(hi));
}

// ---------------- Kernel 0: transpose + hi/lo split of weights ----------------
// wT_hi/lo[c][k] (192x1024) from w_qkv[k][c]; woT_hi/lo[c][k] (1024x64) from w_out[k][c].
__global__ __launch_bounds__(256) void prep_kernel(
    const float* __restrict__ wq, const float* __restrict__ wo,
    ushort_t* __restrict__ wT_hi, ushort_t* __restrict__ wT_lo,
    ushort_t* __restrict__ woT_hi, ushort_t* __restrict__ woT_lo)
{
    const int idx = blockIdx.x * 256 + threadIdx.x;
    if (idx < 192 * DM) {
        const int c = idx >> 10, k = idx & (DM - 1);
        ushort_t h, l; split2(wq[k * 192 + c], h, l);
        wT_hi[idx] = h; wT_lo[idx] = l;              // idx = c*1024 + k
    } else {
        const int j = idx - 192 * DM;                 // < 65536
        const int c = j >> 6, k = j & 63;
        ushort_t h, l; split2(wo[k * ODIM + c], h, l);
        woT_hi[j] = h; woT_lo[j] = l;                 // j = c*64 + k
    }
}

// ---------------- Kernel 1: QKV projection, MFMA hi/lo, no LDS ----------------
// grid 512 x 256. Block: rows R0..R0+16. Wave wv: cols wv*48..+48 (3 ct tiles).
// A-frags read fp32 x directly and split in regs; B-frags direct from wT_hi/lo.
__global__ __launch_bounds__(256) void qkv_kernel(
    const float* __restrict__ x,
    const ushort_t* __restrict__ wT_hi, const ushort_t* __restrict__ wT_lo,
    const float* __restrict__ b,
    ushort_t* __restrict__ q_hi, ushort_t* __restrict__ q_lo,
    ushort_t* __restrict__ k_hi, ushort_t* __restrict__ k_lo,
    ushort_t* __restrict__ vT)
{
    const int tid = threadIdx.x;
    const int wv = tid >> 6, lane = tid & 63, g = lane >> 4, i = lane & 15;
    const int R0 = blockIdx.x * 16;
    const int col0 = wv * 48;
    const f32x4 zero4 = {0.f, 0.f, 0.f, 0.f};
    f32x4 acc[3] = {zero4, zero4, zero4};
    const float* xp = &x[(size_t)(R0 + i) * DM + g * 8];

    for (int kc = 0; kc < 32; ++kc) {
        const float4 xa = *(const float4*)(xp + kc * 32);
        const float4 xb = *(const float4*)(xp + kc * 32 + 4);
        const float xe[8] = {xa.x, xa.y, xa.z, xa.w, xb.x, xb.y, xb.z, xb.w};
        union { short8 v; ushort_t u[8]; } ah, al;
#pragma unroll
        for (int j = 0; j < 8; ++j) { ushort_t h, l; split2(xe[j], h, l); ah.u[j] = h; al.u[j] = l; }
#pragma unroll
        for (int ct = 0; ct < 3; ++ct) {
            const int wrow = col0 + ct * 16 + i;
            const short8 bh = *(const short8*)&wT_hi[wrow * DM + kc * 32 + g * 8];
            const short8 bl = *(const short8*)&wT_lo[wrow * DM + kc * 32 + g * 8];
            acc[ct] = MFMA16(ah.v, bh, acc[ct]);
            acc[ct] = MFMA16(ah.v, bl, acc[ct]);
            acc[ct] = MFMA16(al.v, bh, acc[ct]);
        }
    }
#pragma unroll
    for (int ct = 0; ct < 3; ++ct) {
        const int c = col0 + ct * 16 + i;       // tile is uniform vs the 64/128 splits
        const float bias = b[c];
        if (c < 64) {
#pragma unroll
            for (int reg = 0; reg < 4; ++reg) {
                const int row = R0 + 4 * g + reg;
                ushort_t h, l; split2(acc[ct][reg] + bias, h, l);
                q_hi[row * KD + c] = h; q_lo[row * KD + c] = l;
            }
        } else if (c < 128) {
#pragma unroll
            for (int reg = 0; reg < 4; ++reg) {
                const int row = R0 + 4 * g + reg;
                ushort_t h, l; split2(acc[ct][reg] + bias, h, l);
                k_hi[row * KD + (c - 64)] = h; k_lo[row * KD + (c - 64)] = l;
            }
        } else {
            union { ushort_t u[4]; uint2 v; } pk;
#pragma unroll
            for (int reg = 0; reg < 4; ++reg) pk.u[reg] = f2bf(acc[ct][reg] + bias);
            *(uint2*)&vT[(size_t)(c - 128) * N_TOK + R0 + 4 * g] = pk.v;
        }
    }
}

// ---------------- Kernel 2: causal flash attention, barrier-free K-loop ----------------
// grid 512 x 256 (reversed). Block: one 16-row Q-tile. Wave wv: key tiles t=wv,wv+4,...
// All MFMA fragments loaded directly from global (L2-resident); only P relayout
// (wave-private) touches LDS. Single 4-way merge at the end.
__global__ __launch_bounds__(256) void attn_kernel(
    const ushort_t* __restrict__ q_hi, const ushort_t* __restrict__ q_lo,
    const ushort_t* __restrict__ k_hi, const ushort_t* __restrict__ k_lo,
    const ushort_t* __restrict__ vT, float* __restrict__ ao,
    const int* __restrict__ causal_p)
{
    __shared__ ushort_t Ps[4 * 16 * 76];   // per-wave P relayout (C-layout -> A-layout)
    __shared__ float Om[4 * 16 * 64];      // per-wave partial O
    __shared__ float ml[4 * 32];           // per-wave running m (0..15) and l (16..31)

    const int tid = threadIdx.x;
    const int wv = tid >> 6, lane = tid & 63, g = lane >> 4, i = lane & 15;
    const int qt = (int)gridDim.x - 1 - (int)blockIdx.x;   // heavy blocks first
    const int R0 = qt * 16;
    const int causal = *causal_p;
    const int nkt = causal ? (R0 + 15) / 64 + 1 : (N_TOK / 64);

    const short8 qh0 = *(const short8*)&q_hi[(R0 + i) * KD + g * 8];
    const short8 qh1 = *(const short8*)&q_hi[(R0 + i) * KD + 32 + g * 8];
    const short8 ql0 = *(const short8*)&q_lo[(R0 + i) * KD + g * 8];
    const short8 ql1 = *(const short8*)&q_lo[(R0 + i) * KD + 32 + g * 8];

    const f32x4 zero4 = {0.f, 0.f, 0.f, 0.f};
    f32x4 o4[4] = {zero4, zero4, zero4, zero4};
    float runm[4], runl[4];
#pragma unroll
    for (int r = 0; r < 4; ++r) { runm[r] = -1e30f; runl[r] = 0.f; }

    const int pb = wv * (16 * 76);

    for (int t = wv; t < nkt; t += 4) {
        const int kb = t * 64;
        // S = Q K^T, 3-term hi/lo, K=64 in two 32-chunks
        f32x4 s4[4];
#pragma unroll
        for (int ct = 0; ct < 4; ++ct) {
            const int krow = (kb + ct * 16 + i) * KD;
            const short8 kh0 = *(const short8*)&k_hi[krow + g * 8];
            const short8 kh1 = *(const short8*)&k_hi[krow + 32 + g * 8];
            const short8 kl0 = *(const short8*)&k_lo[krow + g * 8];
            const short8 kl1 = *(const short8*)&k_lo[krow + 32 + g * 8];
            f32x4 a = MFMA16(qh0, kh0, zero4);
            a = MFMA16(qh1, kh1, a);
            a = MFMA16(qh0, kl0, a);
            a = MFMA16(qh1, kl1, a);
            a = MFMA16(ql0, kh0, a);
            a = MFMA16(ql1, kh1, a);
            s4[ct] = a;
        }
        // online softmax: rows r=4g+reg spread over 16 lanes i (+4 ct col-tiles)
#pragma unroll
        for (int reg = 0; reg < 4; ++reg) {
            const int qrow = R0 + 4 * g + reg;
            float mx = -1e30f;
#pragma unroll
            for (int ct = 0; ct < 4; ++ct) {
                const bool vm = (!causal) || (kb + ct * 16 + i <= qrow);
                mx = fmaxf(mx, vm ? s4[ct][reg] : -1e30f);
            }
            mx = fmaxf(mx, __shfl_xor(mx, 1));
            mx = fmaxf(mx, __shfl_xor(mx, 2));
            mx = fmaxf(mx, __shfl_xor(mx, 4));
            mx = fmaxf(mx, __shfl_xor(mx, 8));
            const float nm = fmaxf(runm[reg], mx);
            const float al = __expf(runm[reg] - nm);
            runm[reg] = nm;
            float rs = 0.f;
#pragma unroll
            for (int ct = 0; ct < 4; ++ct) {
                const bool vm = (!causal) || (kb + ct * 16 + i <= qrow);
                const float pv = vm ? __expf(s4[ct][reg] - nm) : 0.f;
                rs += pv;
                Ps[pb + (4 * g + reg) * 76 + ct * 16 + i] = f2bf(pv);
            }
            rs += __shfl_xor(rs, 1);
            rs += __shfl_xor(rs, 2);
            rs += __shfl_xor(rs, 4);
            rs += __shfl_xor(rs, 8);
            runl[reg] = runl[reg] * al + rs;
#pragma unroll
            for (int ct = 0; ct < 4; ++ct) o4[ct][reg] *= al;
        }
        // P: C-layout -> A-layout via wave-private LDS (no barrier needed)
        short8 pf0, pf1;
        {
            union { short8 v8; short4v h[2]; } u0, u1;
            const int pbase = pb + i * 76 + g * 8;
            u0.h[0] = *(const short4v*)&Ps[pbase];
            u0.h[1] = *(const short4v*)&Ps[pbase + 4];
            u1.h[0] = *(const short4v*)&Ps[pbase + 32];
            u1.h[1] = *(const short4v*)&Ps[pbase + 36];
            pf0 = u0.v8; pf1 = u1.v8;
        }
        // O += P V (V single-bf16)
#pragma unroll
        for (int ct = 0; ct < 4; ++ct) {
            const size_t vrow = (size_t)(ct * 16 + i) * N_TOK + kb;
            const short8 vf0 = *(const short8*)&vT[vrow + g * 8];
            const short8 vf1 = *(const short8*)&vT[vrow + 32 + g * 8];
            o4[ct] = MFMA16(pf0, vf0, o4[ct]);
            o4[ct] = MFMA16(pf1, vf1, o4[ct]);
        }
    }

    // 4-way key-split merge
#pragma unroll
    for (int ct = 0; ct < 4; ++ct)
#pragma unroll
        for (int reg = 0; reg < 4; ++reg)
            Om[wv * 1024 + (4 * g + reg) * 64 + ct * 16 + i] = o4[ct][reg];
    if (i == 0) {
#pragma unroll
        for (int reg = 0; reg < 4; ++reg) {
            ml[wv * 32 + 4 * g + reg] = runm[reg];
            ml[wv * 32 + 16 + 4 * g + reg] = runl[reg];
        }
    }
    __syncthreads();
    {
        const int col = tid & 63;
        const int rbase = (tid >> 6) * 4;
#pragma unroll
        for (int rr = 0; rr < 4; ++rr) {
            const int r = rbase + rr;
            const float m0 = ml[r], m1 = ml[32 + r], m2 = ml[64 + r], m3 = ml[96 + r];
            const float M = fmaxf(fmaxf(m0, m1), fmaxf(m2, m3));
            const float e0 = __expf(m0 - M), e1 = __expf(m1 - M);
            const float e2 = __expf(m2 - M), e3 = __expf(m3 - M);
            const float l = ml[16 + r] * e0 + ml[48 + r] * e1 + ml[80 + r] * e2 + ml[112 + r] * e3;
            const float o = Om[r * 64 + col] * e0 + Om[1024 + r * 64 + col] * e1 +
                            Om[2048 + r * 64 + col] * e2 + Om[3072 + r * 64 + col] * e3;
            ao[(R0 + r) * KD + col] = o / l;
        }
    }
}

// ---------------- Kernel 3: output projection, MFMA hi/lo, no LDS ----------------
// grid 512 x 256. Block: 16 rows x 1024 cols; wave wv: cols wv*256..+256 (16 ct tiles).
__global__ __launch_bounds__(256) void proj_kernel(
    const float* __restrict__ ao,
    const ushort_t* __restrict__ woT_hi, const ushort_t* __restrict__ woT_lo,
    const float* __restrict__ b, float* __restrict__ out)
{
    const int tid = threadIdx.x;
    const int wv = tid >> 6, lane = tid & 63, g = lane >> 4, i = lane & 15;
    const int R0 = blockIdx.x * 16;
    const int col0 = wv * 256;

    const float4 a0 = *(const float4*)&ao[(R0 + i) * KD + g * 8];
    const float4 a1 = *(const float4*)&ao[(R0 + i) * KD + g * 8 + 4];
    const float4 a2 = *(const float4*)&ao[(R0 + i) * KD + 32 + g * 8];
    const float4 a3 = *(const float4*)&ao[(R0 + i) * KD + 32 + g * 8 + 4];
    const float xe0[8] = {a0.x, a0.y, a0.z, a0.w, a1.x, a1.y, a1.z, a1.w};
    const float xe1[8] = {a2.x, a2.y, a2.z, a2.w, a3.x, a3.y, a3.z, a3.w};
    union { short8 v; ushort_t u[8]; } ah0, al0, ah1, al1;
#pragma unroll
    for (int j = 0; j < 8; ++j) {
        ushort_t h, l;
        split2(xe0[j], h, l); ah0.u[j] = h; al0.u[j] = l;
        split2(xe1[j], h, l); ah1.u[j] = h; al1.u[j] = l;
    }
    const f32x4 zero4 = {0.f, 0.f, 0.f, 0.f};
#pragma unroll 4
    for (int ct = 0; ct < 16; ++ct) {
        const int c = col0 + ct * 16 + i;
        const short8 bh0 = *(const short8*)&woT_hi[c * KD + g * 8];
        const short8 bh1 = *(const short8*)&woT_hi[c * KD + 32 + g * 8];
        const short8 bl0 = *(const short8*)&woT_lo[c * KD + g * 8];
        const short8 bl1 = *(const short8*)&woT_lo[c * KD + 32 + g * 8];
        f32x4 acc = MFMA16(ah0.v, bh0, zero4);
        acc = MFMA16(ah1.v, bh1, acc);
        acc = MFMA16(ah0.v, bl0, acc);
        acc = MFMA16(ah1.v, bl1, acc);
        acc = MFMA16(al0.v, bh0, acc);
        acc = MFMA16(al1.v, bh1, acc);
        const float bias = b[c];
#pragma unroll
        for (int reg = 0; reg < 4; ++reg)
            out[(R0 + 4 * g + reg) * ODIM + c] = acc[reg] + bias;
    }
}

extern "C" void kernel_launch(void* const* d_in, const int* in_sizes, int n_in,
                              void* d_out, int out_size, void* d_ws, size_t ws_size,
                              hipStream_t stream) {
    const float* x     = (const float*)d_in[0];
    const float* w_qkv = (const float*)d_in[1];
    const float* b_qkv = (const float*)d_in[2];
    const float* w_out = (const float*)d_in[3];
    const float* b_out = (const float*)d_in[4];
    const int* causal  = (const int*)d_in[5];
    float* out         = (float*)d_out;

    char* ws = (char*)d_ws;
    ushort_t* wT_hi  = (ushort_t*)(ws);                  // 192*1024*2 = 384 KB
    ushort_t* wT_lo  = (ushort_t*)(ws + 393216);         // 384 KB
    ushort_t* woT_hi = (ushort_t*)(ws + 786432);         // 128 KB
    ushort_t* woT_lo = (ushort_t*)(ws + 917504);         // 128 KB  (cum 1 MB)
    ushort_t* q_hi   = (ushort_t*)(ws + (1u << 20));     // 1 MB each
    ushort_t* q_lo   = (ushort_t*)(ws + (2u << 20));
    ushort_t* k_hi   = (ushort_t*)(ws + (3u << 20));
    ushort_t* k_lo   = (ushort_t*)(ws + (4u << 20));
    ushort_t* vT     = (ushort_t*)(ws + (5u << 20));
    float*    ao     = (float*)(ws + (6u << 20));        // 2 MB (cum 8 MB)

    prep_kernel<<<1024, 256, 0, stream>>>(w_qkv, w_out, wT_hi, wT_lo, woT_hi, woT_lo);
    qkv_kernel<<<512, 256, 0, stream>>>(x, wT_hi, wT_lo, b_qkv, q_hi, q_lo, k_hi, k_lo, vT);
    attn_kernel<<<512, 256, 0, stream>>>(q_hi, q_lo, k_hi, k_lo, vT, ao, causal);
    proj_kernel<<<512, 256, 0, stream>>>(ao, woT_hi, woT_lo, b_out, out);
}

// Round 5
// 296.277 us; speedup vs baseline: 2.5593x; 1.0214x over previous
//
#include <hip/hip_runtime.h>
#include <hip/hip_bf16.h>

#define N_TOK 8192
#define DM 1024
#define KD 64
#define ODIM 1024

typedef unsigned short ushort_t;
typedef __attribute__((ext_vector_type(8))) short short8;
typedef __attribute__((ext_vector_type(4))) short short4v;
typedef __attribute__((ext_vector_type(4))) float f32x4;

#define MFMA16(a, b, c) __builtin_amdgcn_mfma_f32_16x16x32_bf16((a), (b), (c), 0, 0, 0)

__device__ __forceinline__ ushort_t f2bf(float x) {
    __hip_bfloat16 h = __float2bfloat16(x);
    return *(ushort_t*)&h;
}
__device__ __forceinline__ float bf2f(ushort_t u) {
    __hip_bfloat16 h = *(__hip_bfloat16*)&u;
    return __bfloat162float(h);
}
// Dekker-style split: x ~= hi + lo, both bf16. Residual ~2^-17 relative.
__device__ __forceinline__ void split2(float x, ushort_t& hi, ushort_t& lo) {
    hi = f2bf(x);
    lo = f2bf(x - bf2f(hi));
}

// ---------------- Kernel 0: transpose + hi/lo split of weights ----------------
__global__ __launch_bounds__(256) void prep_kernel(
    const float* __restrict__ wq, const float* __restrict__ wo,
    ushort_t* __restrict__ wT_hi, ushort_t* __restrict__ wT_lo,
    ushort_t* __restrict__ woT_hi, ushort_t* __restrict__ woT_lo)
{
    const int idx = blockIdx.x * 256 + threadIdx.x;
    if (idx < 192 * DM) {
        const int c = idx >> 10, k = idx & (DM - 1);
        ushort_t h, l; split2(wq[k * 192 + c], h, l);
        wT_hi[idx] = h; wT_lo[idx] = l;              // idx = c*1024 + k
    } else {
        const int j = idx - 192 * DM;                 // < 65536
        const int c = j >> 6, k = j & 63;
        ushort_t h, l; split2(wo[k * ODIM + c], h, l);
        woT_hi[j] = h; woT_lo[j] = l;                 // j = c*64 + k
    }
}

// ---------------- Kernel 1: QKV projection, MFMA hi/lo ----------------
// grid 1536 x 256. Block: rows (b/3)*16..+16; wave: one 16-col tile ctid=(b%3)*4+wv.
__global__ __launch_bounds__(256) void qkv_kernel(
    const float* __restrict__ x,
    const ushort_t* __restrict__ wT_hi, const ushort_t* __restrict__ wT_lo,
    const float* __restrict__ b,
    ushort_t* __restrict__ q_hi, ushort_t* __restrict__ q_lo,
    ushort_t* __restrict__ k_hi, ushort_t* __restrict__ k_lo,
    ushort_t* __restrict__ vT)
{
    const int tid = threadIdx.x;
    const int wv = tid >> 6, lane = tid & 63, g = lane >> 4, i = lane & 15;
    const int bb = (int)blockIdx.x;
    const int R0 = (bb / 3) * 16;
    const int ctid = (bb % 3) * 4 + wv;   // 0..11
    const f32x4 zero4 = {0.f, 0.f, 0.f, 0.f};
    f32x4 acc = zero4;
    const float* xp = &x[(size_t)(R0 + i) * DM + g * 8];
    const ushort_t* bhp = &wT_hi[(ctid * 16 + i) * DM + g * 8];
    const ushort_t* blp = &wT_lo[(ctid * 16 + i) * DM + g * 8];

    for (int kc = 0; kc < 32; ++kc) {
        const float4 xa = *(const float4*)(xp + kc * 32);
        const float4 xb = *(const float4*)(xp + kc * 32 + 4);
        const float xe[8] = {xa.x, xa.y, xa.z, xa.w, xb.x, xb.y, xb.z, xb.w};
        union { short8 v; ushort_t u[8]; } ah, al;
#pragma unroll
        for (int j = 0; j < 8; ++j) { ushort_t h, l; split2(xe[j], h, l); ah.u[j] = h; al.u[j] = l; }
        const short8 bh = *(const short8*)(bhp + kc * 32);
        const short8 bl = *(const short8*)(blp + kc * 32);
        acc = MFMA16(ah.v, bh, acc);
        acc = MFMA16(ah.v, bl, acc);
        acc = MFMA16(al.v, bh, acc);
    }
    const int c = ctid * 16 + i;
    const float bias = b[c];
    if (ctid < 4) {
#pragma unroll
        for (int reg = 0; reg < 4; ++reg) {
            ushort_t h, l; split2(acc[reg] + bias, h, l);
            q_hi[(R0 + 4 * g + reg) * KD + c] = h;
            q_lo[(R0 + 4 * g + reg) * KD + c] = l;
        }
    } else if (ctid < 8) {
        const int c2 = c - 64;
#pragma unroll
        for (int reg = 0; reg < 4; ++reg) {
            ushort_t h, l; split2(acc[reg] + bias, h, l);
            k_hi[(R0 + 4 * g + reg) * KD + c2] = h;
            k_lo[(R0 + 4 * g + reg) * KD + c2] = l;
        }
    } else {
        union { ushort_t u[4]; uint2 v; } pk;
#pragma unroll
        for (int reg = 0; reg < 4; ++reg) pk.u[reg] = f2bf(acc[reg] + bias);
        *(uint2*)&vT[(size_t)(c - 128) * N_TOK + R0 + 4 * g] = pk.v;
    }
}

// ---------------- Kernel 2: split-K causal flash attention ----------------
// grid 2048 x 256. Block b: Q-tile qt=511-(b>>2) (heavy first), key-split s=b&3.
// Chunk [s*nkt/4, (s+1)*nkt/4) of 64-key tiles; 4 waves interleave within chunk.
// Writes UNNORMALIZED partial (M, L, O) per (qt, s). No barriers in K-loop.
__global__ __launch_bounds__(256) void attn_kernel(
    const ushort_t* __restrict__ q_hi, const ushort_t* __restrict__ q_lo,
    const ushort_t* __restrict__ k_hi, const ushort_t* __restrict__ k_lo,
    const ushort_t* __restrict__ vT,
    float* __restrict__ Opart, float* __restrict__ MLpart,
    const int* __restrict__ causal_p)
{
    __shared__ ushort_t Ps[4 * 16 * 76];   // per-wave P relayout
    __shared__ float Om[4 * 16 * 64];      // per-wave partial O
    __shared__ float ml[4 * 32];           // per-wave m (0..15), l (16..31)

    const int tid = threadIdx.x;
    const int wv = tid >> 6, lane = tid & 63, g = lane >> 4, i = lane & 15;
    const int bidx = (int)blockIdx.x;
    const int qt = 511 - (bidx >> 2);
    const int s = bidx & 3;
    const int R0 = qt * 16;
    const int causal = *causal_p;
    const int nkt = causal ? (R0 >> 6) + 1 : (N_TOK / 64);
    const int c0 = (s * nkt) >> 2;
    const int c1 = ((s + 1) * nkt) >> 2;

    const short8 qh0 = *(const short8*)&q_hi[(R0 + i) * KD + g * 8];
    const short8 qh1 = *(const short8*)&q_hi[(R0 + i) * KD + 32 + g * 8];
    const short8 ql0 = *(const short8*)&q_lo[(R0 + i) * KD + g * 8];
    const short8 ql1 = *(const short8*)&q_lo[(R0 + i) * KD + 32 + g * 8];

    const f32x4 zero4 = {0.f, 0.f, 0.f, 0.f};
    f32x4 o4[4] = {zero4, zero4, zero4, zero4};
    float runm[4], runl[4];
#pragma unroll
    for (int r = 0; r < 4; ++r) { runm[r] = -1e30f; runl[r] = 0.f; }

    const int pb = wv * (16 * 76);

    for (int t = c0 + wv; t < c1; t += 4) {
        const int kb = t * 64;
        f32x4 s4[4];
#pragma unroll
        for (int ct = 0; ct < 4; ++ct) {
            const int krow = (kb + ct * 16 + i) * KD;
            const short8 kh0 = *(const short8*)&k_hi[krow + g * 8];
            const short8 kh1 = *(const short8*)&k_hi[krow + 32 + g * 8];
            const short8 kl0 = *(const short8*)&k_lo[krow + g * 8];
            const short8 kl1 = *(const short8*)&k_lo[krow + 32 + g * 8];
            f32x4 a = MFMA16(qh0, kh0, zero4);
            a = MFMA16(qh1, kh1, a);
            a = MFMA16(qh0, kl0, a);
            a = MFMA16(qh1, kl1, a);
            a = MFMA16(ql0, kh0, a);
            a = MFMA16(ql1, kh1, a);
            s4[ct] = a;
        }
#pragma unroll
        for (int reg = 0; reg < 4; ++reg) {
            const int qrow = R0 + 4 * g + reg;
            float mx = -1e30f;
#pragma unroll
            for (int ct = 0; ct < 4; ++ct) {
                const bool vm = (!causal) || (kb + ct * 16 + i <= qrow);
                mx = fmaxf(mx, vm ? s4[ct][reg] : -1e30f);
            }
            mx = fmaxf(mx, __shfl_xor(mx, 1));
            mx = fmaxf(mx, __shfl_xor(mx, 2));
            mx = fmaxf(mx, __shfl_xor(mx, 4));
            mx = fmaxf(mx, __shfl_xor(mx, 8));
            const float nm = fmaxf(runm[reg], mx);
            const float al = __expf(runm[reg] - nm);
            runm[reg] = nm;
            float rs = 0.f;
#pragma unroll
            for (int ct = 0; ct < 4; ++ct) {
                const bool vm = (!causal) || (kb + ct * 16 + i <= qrow);
                const float pv = vm ? __expf(s4[ct][reg] - nm) : 0.f;
                rs += pv;
                Ps[pb + (4 * g + reg) * 76 + ct * 16 + i] = f2bf(pv);
            }
            rs += __shfl_xor(rs, 1);
            rs += __shfl_xor(rs, 2);
            rs += __shfl_xor(rs, 4);
            rs += __shfl_xor(rs, 8);
            runl[reg] = runl[reg] * al + rs;
#pragma unroll
            for (int ct = 0; ct < 4; ++ct) o4[ct][reg] *= al;
        }
        short8 pf0, pf1;
        {
            union { short8 v8; short4v h[2]; } u0, u1;
            const int pbase = pb + i * 76 + g * 8;
            u0.h[0] = *(const short4v*)&Ps[pbase];
            u0.h[1] = *(const short4v*)&Ps[pbase + 4];
            u1.h[0] = *(const short4v*)&Ps[pbase + 32];
            u1.h[1] = *(const short4v*)&Ps[pbase + 36];
            pf0 = u0.v8; pf1 = u1.v8;
        }
#pragma unroll
        for (int ct = 0; ct < 4; ++ct) {
            const size_t vrow = (size_t)(ct * 16 + i) * N_TOK + kb;
            const short8 vf0 = *(const short8*)&vT[vrow + g * 8];
            const short8 vf1 = *(const short8*)&vT[vrow + 32 + g * 8];
            o4[ct] = MFMA16(pf0, vf0, o4[ct]);
            o4[ct] = MFMA16(pf1, vf1, o4[ct]);
        }
    }

    // block-level 4-way wave combine -> unnormalized partial for (qt, s)
#pragma unroll
    for (int ct = 0; ct < 4; ++ct)
#pragma unroll
        for (int reg = 0; reg < 4; ++reg)
            Om[wv * 1024 + (4 * g + reg) * 64 + ct * 16 + i] = o4[ct][reg];
    if (i == 0) {
#pragma unroll
        for (int reg = 0; reg < 4; ++reg) {
            ml[wv * 32 + 4 * g + reg] = runm[reg];
            ml[wv * 32 + 16 + 4 * g + reg] = runl[reg];
        }
    }
    __syncthreads();
    {
        const int col = tid & 63;
        const int rbase = (tid >> 6) * 4;
        const int pidx = qt * 4 + s;
#pragma unroll
        for (int rr = 0; rr < 4; ++rr) {
            const int r = rbase + rr;
            const float m0 = ml[r], m1 = ml[32 + r], m2 = ml[64 + r], m3 = ml[96 + r];
            const float M = fmaxf(fmaxf(m0, m1), fmaxf(m2, m3));
            const float e0 = __expf(m0 - M), e1 = __expf(m1 - M);
            const float e2 = __expf(m2 - M), e3 = __expf(m3 - M);
            const float L = ml[16 + r] * e0 + ml[48 + r] * e1 + ml[80 + r] * e2 + ml[112 + r] * e3;
            const float O = Om[r * 64 + col] * e0 + Om[1024 + r * 64 + col] * e1 +
                            Om[2048 + r * 64 + col] * e2 + Om[3072 + r * 64 + col] * e3;
            Opart[(size_t)pidx * 1024 + r * 64 + col] = O;
            if (col == 0) {
                MLpart[pidx * 32 + r] = M;
                MLpart[pidx * 32 + 16 + r] = L;
            }
        }
    }
}

// ---------------- Kernel 2b: split-K merge -> ao (bf16 hi/lo) ----------------
// grid 512 x 256. Block = one Q-tile; combine 4 split partials, normalize, split.
__global__ __launch_bounds__(256) void merge_kernel(
    const float* __restrict__ Opart, const float* __restrict__ MLpart,
    ushort_t* __restrict__ ao_hi, ushort_t* __restrict__ ao_lo)
{
    const int qt = (int)blockIdx.x;
    const int tid = threadIdx.x;
    const int col = tid & 63;
    const int rbase = (tid >> 6) * 4;
#pragma unroll
    for (int rr = 0; rr < 4; ++rr) {
        const int r = rbase + rr;
        float m[4], l[4];
#pragma unroll
        for (int s2 = 0; s2 < 4; ++s2) {
            m[s2] = MLpart[(qt * 4 + s2) * 32 + r];
            l[s2] = MLpart[(qt * 4 + s2) * 32 + 16 + r];
        }
        const float M = fmaxf(fmaxf(m[0], m[1]), fmaxf(m[2], m[3]));
        float den = 0.f, o = 0.f;
#pragma unroll
        for (int s2 = 0; s2 < 4; ++s2) {
            const float e = __expf(m[s2] - M);
            den += l[s2] * e;
            o += Opart[(size_t)(qt * 4 + s2) * 1024 + r * 64 + col] * e;
        }
        const float val = o / den;
        ushort_t h, lo2; split2(val, h, lo2);
        ao_hi[(qt * 16 + r) * KD + col] = h;
        ao_lo[(qt * 16 + r) * KD + col] = lo2;
    }
}

// ---------------- Kernel 3: output projection, MFMA hi/lo ----------------
// grid 2048 x 256. Block: rows (b>>2)*16, col quarter (b&3)*256; wave: 4 ct tiles.
__global__ __launch_bounds__(256) void proj_kernel(
    const ushort_t* __restrict__ ao_hi, const ushort_t* __restrict__ ao_lo,
    const ushort_t* __restrict__ woT_hi, const ushort_t* __restrict__ woT_lo,
    const float* __restrict__ b, float* __restrict__ out)
{
    const int tid = threadIdx.x;
    const int wv = tid >> 6, lane = tid & 63, g = lane >> 4, i = lane & 15;
    const int bb = (int)blockIdx.x;
    const int R0 = (bb >> 2) * 16;
    const int ct0 = (bb & 3) * 16 + wv * 4;

    const short8 ah0 = *(const short8*)&ao_hi[(R0 + i) * KD + g * 8];
    const short8 ah1 = *(const short8*)&ao_hi[(R0 + i) * KD + 32 + g * 8];
    const short8 al0 = *(const short8*)&ao_lo[(R0 + i) * KD + g * 8];
    const short8 al1 = *(const short8*)&ao_lo[(R0 + i) * KD + 32 + g * 8];

    const f32x4 zero4 = {0.f, 0.f, 0.f, 0.f};
#pragma unroll
    for (int cc = 0; cc < 4; ++cc) {
        const int c = (ct0 + cc) * 16 + i;
        const short8 bh0 = *(const short8*)&woT_hi[c * KD + g * 8];
        const short8 bh1 = *(const short8*)&woT_hi[c * KD + 32 + g * 8];
        const short8 bl0 = *(const short8*)&woT_lo[c * KD + g * 8];
        const short8 bl1 = *(const short8*)&woT_lo[c * KD + 32 + g * 8];
        f32x4 acc = MFMA16(ah0, bh0, zero4);
        acc = MFMA16(ah1, bh1, acc);
        acc = MFMA16(ah0, bl0, acc);
        acc = MFMA16(ah1, bl1, acc);
        acc = MFMA16(al0, bh0, acc);
        acc = MFMA16(al1, bh1, acc);
        const float bias = b[c];
#pragma unroll
        for (int reg = 0; reg < 4; ++reg)
            out[(R0 + 4 * g + reg) * ODIM + c] = acc[reg] + bias;
    }
}

extern "C" void kernel_launch(void* const* d_in, const int* in_sizes, int n_in,
                              void* d_out, int out_size, void* d_ws, size_t ws_size,
                              hipStream_t stream) {
    const float* x     = (const float*)d_in[0];
    const float* w_qkv = (const float*)d_in[1];
    const float* b_qkv = (const float*)d_in[2];
    const float* w_out = (const float*)d_in[3];
    const float* b_out = (const float*)d_in[4];
    const int* causal  = (const int*)d_in[5];
    float* out         = (float*)d_out;

    char* ws = (char*)d_ws;
    ushort_t* wT_hi  = (ushort_t*)(ws);                    // 384 KB
    ushort_t* wT_lo  = (ushort_t*)(ws + 393216);           // 384 KB
    ushort_t* woT_hi = (ushort_t*)(ws + 786432);           // 128 KB
    ushort_t* woT_lo = (ushort_t*)(ws + 917504);           // 128 KB -> 1 MB
    ushort_t* q_hi   = (ushort_t*)(ws + (1u << 20));
    ushort_t* q_lo   = (ushort_t*)(ws + (2u << 20));
    ushort_t* k_hi   = (ushort_t*)(ws + (3u << 20));
    ushort_t* k_lo   = (ushort_t*)(ws + (4u << 20));
    ushort_t* vT     = (ushort_t*)(ws + (5u << 20));       // -> 6 MB
    ushort_t* ao_hi  = (ushort_t*)(ws + (6u << 20));       // 1 MB
    ushort_t* ao_lo  = (ushort_t*)(ws + (7u << 20));       // 1 MB -> 8 MB
    float*    Opart  = (float*)(ws + (8u << 20));          // 2048*1024*4 = 8 MB -> 16 MB
    float*    MLpart = (float*)(ws + (16u << 20));         // 256 KB

    prep_kernel<<<1024, 256, 0, stream>>>(w_qkv, w_out, wT_hi, wT_lo, woT_hi, woT_lo);
    qkv_kernel<<<1536, 256, 0, stream>>>(x, wT_hi, wT_lo, b_qkv, q_hi, q_lo, k_hi, k_lo, vT);
    attn_kernel<<<2048, 256, 0, stream>>>(q_hi, q_lo, k_hi, k_lo, vT, Opart, MLpart, causal);
    merge_kernel<<<512, 256, 0, stream>>>(Opart, MLpart, ao_hi, ao_lo);
    proj_kernel<<<2048, 256, 0, stream>>>(ao_hi, ao_lo, woT_hi, woT_lo, b_out, out);
}